// Round 1
// baseline (965.888 us; speedup 1.0000x reference)
//
#include <hip/hip_runtime.h>
#include <math.h>

#define K_NN 11
#define B_   1024
#define D_   64
#define A_   4
#define C_   50000
#define BT   256                    // threads per block = batch rows per block (K1)
#define NB   (B_ / BT)              // 4 batch tiles
#define NCH  32                     // C chunks (parallelism + partial top-k)
#define CHUNK ((C_ + NCH - 1) / NCH)  // 1563
#define SUBC 128                    // staged table rows per LDS iteration

// ---------------- K1: fused scores + per-thread top-k ----------------
__global__ __launch_bounds__(BT) void qec_topk_kernel(
    const float* __restrict__ obs, const float* __restrict__ ts,
    float* __restrict__ pscore, int* __restrict__ pidx)
{
  __shared__ float sS[SUBC * 64];
  __shared__ float sS2[SUBC];

  const int tid = threadIdx.x;
  const int bid = blockIdx.x;
  const int ch  = bid % NCH;
  const int a   = (bid / NCH) % A_;
  const int bb  = bid / (NCH * A_);
  const int b   = bb * BT + tid;

  // obs row in registers (static indexing only)
  float o[64];
  {
    const float4* orow = (const float4*)(obs + (size_t)b * 64);
    #pragma unroll
    for (int i = 0; i < 16; ++i) {
      float4 v = orow[i];
      o[4*i+0] = v.x; o[4*i+1] = v.y; o[4*i+2] = v.z; o[4*i+3] = v.w;
    }
  }

  float best[K_NN]; int bix[K_NN];
  #pragma unroll
  for (int j = 0; j < K_NN; ++j) { best[j] = INFINITY; bix[j] = 0; }

  const int c0   = ch * CHUNK;
  const int cend = min(C_, c0 + CHUNK);
  const float* tsa = ts + (size_t)a * C_ * 64;

  for (int cc = c0; cc < cend; cc += SUBC) {
    const int nrows = min(SUBC, cend - cc);

    // stage table rows -> LDS (coalesced float4)
    {
      const float4* g4 = (const float4*)(tsa + (size_t)cc * 64);
      float4* l4 = (float4*)sS;
      const int n4 = nrows * 16;
      for (int i = tid; i < n4; i += BT) l4[i] = g4[i];
    }
    __syncthreads();

    // s2 per staged row (rotated indexing -> conflict-free)
    if (tid < nrows) {
      float acc = 0.f;
      #pragma unroll
      for (int j = 0; j < 64; ++j) {
        int d = (tid + j) & 63;
        float v = sS[tid * 64 + d];
        acc = fmaf(v, v, acc);
      }
      sS2[tid] = acc;
    }
    __syncthreads();

    // dots + running top-k (LDS reads are wave-uniform -> broadcast)
    for (int r = 0; r < nrows; ++r) {
      const float4* srow = (const float4*)(sS + r * 64);
      float a0 = 0.f, a1 = 0.f, a2 = 0.f, a3 = 0.f;
      #pragma unroll
      for (int d4 = 0; d4 < 16; ++d4) {
        float4 sv = srow[d4];
        a0 = fmaf(sv.x, o[4*d4+0], a0);
        a1 = fmaf(sv.y, o[4*d4+1], a1);
        a2 = fmaf(sv.z, o[4*d4+2], a2);
        a3 = fmaf(sv.w, o[4*d4+3], a3);
      }
      float dot = (a0 + a1) + (a2 + a3);
      float sc  = sS2[r] - 2.0f * dot;         // ordering == d2 ordering (x2 const per b)
      if (sc < best[K_NN-1]) {                 // strict < : stable (lower c wins ties)
        int ci = cc + r;
        #pragma unroll
        for (int j = K_NN-1; j >= 1; --j) {
          bool  s1 = best[j-1] > sc;
          float nb = s1 ? best[j-1] : sc;
          int   ni = s1 ? bix[j-1]  : ci;
          if (best[j] > sc) { best[j] = nb; bix[j] = ni; }
        }
        if (best[0] > sc) { best[0] = sc; bix[0] = ci; }
      }
    }
    __syncthreads();
  }

  const size_t base = (((size_t)b * A_ + a) * NCH + ch) * K_NN;
  #pragma unroll
  for (int j = 0; j < K_NN; ++j) { pscore[base+j] = best[j]; pidx[base+j] = bix[j]; }
}

// ---------------- K2: merge partial top-k, gather qvals, mean ----------------
__global__ __launch_bounds__(256) void merge_kernel(
    const float* __restrict__ pscore, const int* __restrict__ pidx,
    const float* __restrict__ qvals, float* __restrict__ qec)
{
  const int tt = blockIdx.x * 256 + threadIdx.x;  // tt = b*A + a
  if (tt >= B_ * A_) return;
  const int a = tt % A_;

  float best[K_NN]; int bix[K_NN];
  #pragma unroll
  for (int j = 0; j < K_NN; ++j) { best[j] = INFINITY; bix[j] = 0x7fffffff; }

  const float* ps = pscore + (size_t)tt * NCH * K_NN;
  const int*   pi = pidx   + (size_t)tt * NCH * K_NN;

  for (int e = 0; e < NCH * K_NN; ++e) {
    float sc = ps[e]; int ci = pi[e];
    bool lt_last = (sc < best[K_NN-1]) || (sc == best[K_NN-1] && ci < bix[K_NN-1]);
    if (lt_last) {
      #pragma unroll
      for (int j = K_NN-1; j >= 1; --j) {
        bool  s1 = (best[j-1] > sc) || (best[j-1] == sc && bix[j-1] > ci);
        float nb = s1 ? best[j-1] : sc;
        int   ni = s1 ? bix[j-1]  : ci;
        bool  wr = (best[j] > sc) || (best[j] == sc && bix[j] > ci);
        if (wr) { best[j] = nb; bix[j] = ni; }
      }
      bool w0 = (best[0] > sc) || (best[0] == sc && bix[0] > ci);
      if (w0) { best[0] = sc; bix[0] = ci; }
    }
  }

  const float* qa = qvals + (size_t)a * C_;
  float s = 0.f;
  #pragma unroll
  for (int j = 0; j < K_NN; ++j) s += qa[bix[j]];
  qec[tt] = s / (float)K_NN;
}

// ---------------- K3: MLP + combine + argmax ----------------
__global__ __launch_bounds__(256) void mlp_kernel(
    const float* __restrict__ obs, const float* __restrict__ qec,
    const float* __restrict__ W1, const float* __restrict__ b1,
    const float* __restrict__ W2, const float* __restrict__ b2,
    const float* __restrict__ W3, const float* __restrict__ b3,
    float* __restrict__ out)
{
  const int wave = threadIdx.x >> 6;
  const int lane = threadIdx.x & 63;
  const int b = blockIdx.x * 4 + wave;

  float x = obs[(size_t)b * 64 + lane];

  float acc = b1[lane];
  #pragma unroll 8
  for (int d = 0; d < 64; ++d)
    acc = fmaf(__shfl(x, d, 64), W1[d * 64 + lane], acc);
  float h1 = fmaxf(acc, 0.f);

  float acc2 = b2[lane];
  #pragma unroll 8
  for (int d = 0; d < 64; ++d)
    acc2 = fmaf(__shfl(h1, d, 64), W2[d * 64 + lane], acc2);
  float h2 = fmaxf(acc2, 0.f);

  float p0 = h2 * W3[lane * 4 + 0];
  float p1 = h2 * W3[lane * 4 + 1];
  float p2 = h2 * W3[lane * 4 + 2];
  float p3 = h2 * W3[lane * 4 + 3];
  #pragma unroll
  for (int off = 32; off > 0; off >>= 1) {
    p0 += __shfl_xor(p0, off, 64);
    p1 += __shfl_xor(p1, off, 64);
    p2 += __shfl_xor(p2, off, 64);
    p3 += __shfl_xor(p3, off, 64);
  }

  if (lane == 0) {
    float q0 = 0.5f * (qec[b * 4 + 0] + (p0 + b3[0]));
    float q1 = 0.5f * (qec[b * 4 + 1] + (p1 + b3[1]));
    float q2 = 0.5f * (qec[b * 4 + 2] + (p2 + b3[2]));
    float q3 = 0.5f * (qec[b * 4 + 3] + (p3 + b3[3]));
    int am = 0; float m = q0;
    if (q1 > m) { m = q1; am = 1; }
    if (q2 > m) { m = q2; am = 2; }
    if (q3 > m) { m = q3; am = 3; }
    out[b] = (float)am;                       // action as float (tuple promoted to f32)
    float* qrow = out + B_ + (size_t)b * 4;
    qrow[0] = q0; qrow[1] = q1; qrow[2] = q2; qrow[3] = q3;
  }
}

extern "C" void kernel_launch(void* const* d_in, const int* in_sizes, int n_in,
                              void* d_out, int out_size, void* d_ws, size_t ws_size,
                              hipStream_t stream) {
  const float* obs = (const float*)d_in[0];
  const float* ts  = (const float*)d_in[1];
  const float* qv  = (const float*)d_in[2];
  const float* W1  = (const float*)d_in[3];
  const float* b1  = (const float*)d_in[4];
  const float* W2  = (const float*)d_in[5];
  const float* b2  = (const float*)d_in[6];
  const float* W3  = (const float*)d_in[7];
  const float* b3  = (const float*)d_in[8];
  float* out = (float*)d_out;

  // workspace layout
  float* qec    = (float*)d_ws;                                   // B*A floats
  float* pscore = qec + (size_t)B_ * A_;                          // B*A*NCH*K floats
  int*   pidx   = (int*)(pscore + (size_t)B_ * A_ * NCH * K_NN);  // same count

  qec_topk_kernel<<<dim3(NB * A_ * NCH), dim3(BT), 0, stream>>>(obs, ts, pscore, pidx);
  merge_kernel<<<dim3((B_ * A_ + 255) / 256), dim3(256), 0, stream>>>(pscore, pidx, qv, qec);
  mlp_kernel<<<dim3(B_ / 4), dim3(256), 0, stream>>>(obs, qec, W1, b1, W2, b2, W3, b3, out);
}

// Round 2
// 767.435 us; speedup vs baseline: 1.2586x; 1.2586x over previous
//
#include <hip/hip_runtime.h>
#include <math.h>

#define K_NN 11
#define B_   1024
#define D_   64
#define A_   4
#define C_   50000
#define NT   ((C_ + 63) / 64)          // 782 candidate tiles of 64

// ---------------- K0: s2[a,c] = sum(ts[a,c,:]^2) ----------------
__global__ __launch_bounds__(256) void s2_kernel(const float* __restrict__ ts,
                                                 float* __restrict__ s2g) {
  const int gwid = (blockIdx.x * 256 + threadIdx.x) >> 6;  // global wave id
  const int lane = threadIdx.x & 63;
  const int r0 = gwid * 16;                                 // 16 rows per wave
  if (r0 >= A_ * C_) return;
  const float4* t4 = (const float4*)ts;
  #pragma unroll
  for (int i = 0; i < 4; ++i) {
    const int fi = i * 64 + lane;             // float4 idx in 16-row block
    const int r  = r0 + (fi >> 4);
    const int k  = fi & 15;
    float4 v = t4[(size_t)r * 16 + k];
    float acc = v.x*v.x + v.y*v.y + v.z*v.z + v.w*v.w;
    #pragma unroll
    for (int off = 1; off < 16; off <<= 1) acc += __shfl_xor(acc, off, 64);
    if ((lane & 15) == 0) s2g[r] = acc;
  }
}

// ---------------- K1: transposed fused scores + shared-tau top-k ----------------
// grid: 256 blocks (64 b-groups x 4 actions), 512 threads (8 waves), wave = 2 b-rows.
// lane = candidate within 64-wide tile; obs rows broadcast in VGPRs.

#define SELECT_INSERT(SCV, BEST, BIX, C0)                                   \
  {                                                                         \
    unsigned long long m_ = __ballot((SCV) < BEST[K_NN-1]);                 \
    while (m_) {                                                            \
      const int l_ = __ffsll(m_) - 1;                                       \
      m_ &= m_ - 1;                                                         \
      const float ssc = __uint_as_float(                                    \
          __builtin_amdgcn_readlane(__float_as_uint(SCV), l_));             \
      const int sidx = (C0) + l_;                                           \
      if (ssc < BEST[K_NN-1]) {                                             \
        _Pragma("unroll")                                                   \
        for (int j = K_NN-1; j >= 1; --j) {                                 \
          const bool  sh = BEST[j-1] > ssc;                                 \
          const float nb = sh ? BEST[j-1] : ssc;                            \
          const int   ni = sh ? BIX[j-1]  : sidx;                           \
          const bool  wr = BEST[j] > ssc;                                   \
          BEST[j] = wr ? nb : BEST[j];                                      \
          BIX[j]  = wr ? ni : BIX[j];                                       \
        }                                                                   \
        const bool w0 = BEST[0] > ssc;                                      \
        BIX[0]  = w0 ? sidx : BIX[0];                                       \
        BEST[0] = w0 ? ssc  : BEST[0];                                      \
      }                                                                     \
    }                                                                       \
  }

__global__ __launch_bounds__(512, 2) void qec_kernel(
    const float* __restrict__ obs, const float* __restrict__ ts,
    const float* __restrict__ s2g, const float* __restrict__ qv,
    float* __restrict__ qec)
{
  __shared__ float sbuf[2][64 * 64];        // 32 KB, XOR-swizzled float4 slots

  const int tid  = threadIdx.x;
  const int lane = tid & 63;
  const int w    = tid >> 6;                // wave 0..7
  const int a    = blockIdx.x >> 6;         // 0..3
  const int bg   = blockIdx.x & 63;         // b-group 0..63
  const int b0   = bg * 16 + w * 2;
  const int b1   = b0 + 1;

  const float* tsa = ts  + (size_t)a * C_ * 64;
  const float* s2a = s2g + (size_t)a * C_;

  // obs rows -> broadcast VGPRs
  float o0[64], o1[64];
  {
    const float4* p0 = (const float4*)(obs + (size_t)b0 * 64);
    const float4* p1 = (const float4*)(obs + (size_t)b1 * 64);
    #pragma unroll
    for (int i = 0; i < 16; ++i) {
      float4 v0 = p0[i], v1 = p1[i];
      o0[4*i]=v0.x; o0[4*i+1]=v0.y; o0[4*i+2]=v0.z; o0[4*i+3]=v0.w;
      o1[4*i]=v1.x; o1[4*i+1]=v1.y; o1[4*i+2]=v1.z; o1[4*i+3]=v1.w;
    }
  }

  float best0[K_NN], best1[K_NN]; int bix0[K_NN], bix1[K_NN];
  #pragma unroll
  for (int j = 0; j < K_NN; ++j) {
    best0[j] = INFINITY; best1[j] = INFINITY; bix0[j] = 0; bix1[j] = 0;
  }

  // per-lane swizzled read offsets (float4 index): row=lane, slot=d4^(lane&7)
  int offi[16];
  #pragma unroll
  for (int d4 = 0; d4 < 16; ++d4) offi[d4] = lane * 16 + (d4 ^ (lane & 7));

  // staging slots for this thread (float4-slot index space, 1024 slots/tile)
  const int sl0 = w * 64 + lane;
  const int sl1 = sl0 + 512;
  const int r0s = sl0 >> 4, d40 = (sl0 & 15) ^ (r0s & 7);
  const int r1s = sl1 >> 4, d41 = (sl1 & 15) ^ (r1s & 7);

  // prologue: load tile 0 into regs
  float4 st0, st1;
  {
    int c0r0 = r0s; if (c0r0 > C_-1) c0r0 = C_-1;   // t=0: c = r
    int c0r1 = r1s; if (c0r1 > C_-1) c0r1 = C_-1;
    st0 = *(const float4*)(tsa + (size_t)c0r0 * 64 + d40 * 4);
    st1 = *(const float4*)(tsa + (size_t)c0r1 * 64 + d41 * 4);
  }

#define BODY(BUF)                                                            \
  {                                                                          \
    const int t  = tt + (BUF);                                               \
    const int c0 = t * 64;                                                   \
    /* write staged regs (tile t) into buffer BUF */                         \
    float4* sp = (float4*)&sbuf[BUF][0];                                     \
    sp[sl0] = st0; sp[sl1] = st1;                                            \
    /* issue next tile's global loads early */                               \
    {                                                                        \
      int tn = t + 1; if (tn > NT-1) tn = NT-1;                              \
      int cn0 = tn*64 + r0s; if (cn0 > C_-1) cn0 = C_-1;                     \
      int cn1 = tn*64 + r1s; if (cn1 > C_-1) cn1 = C_-1;                     \
      st0 = *(const float4*)(tsa + (size_t)cn0 * 64 + d40 * 4);              \
      st1 = *(const float4*)(tsa + (size_t)cn1 * 64 + d41 * 4);              \
    }                                                                        \
    int cs2 = c0 + lane; if (cs2 > C_-1) cs2 = C_-1;                         \
    const float s2v = s2a[cs2];                                              \
    __syncthreads();                                                         \
    /* compute tile t: lane's candidate = c0+lane */                         \
    float acc0 = 0.f, acc1 = 0.f;                                            \
    const float4* rp = (const float4*)&sbuf[BUF][0];                         \
    _Pragma("unroll")                                                        \
    for (int d4 = 0; d4 < 16; ++d4) {                                        \
      const float4 cv = rp[offi[d4]];                                        \
      acc0 = fmaf(cv.x, o0[4*d4+0], acc0);                                   \
      acc1 = fmaf(cv.x, o1[4*d4+0], acc1);                                   \
      acc0 = fmaf(cv.y, o0[4*d4+1], acc0);                                   \
      acc1 = fmaf(cv.y, o1[4*d4+1], acc1);                                   \
      acc0 = fmaf(cv.z, o0[4*d4+2], acc0);                                   \
      acc1 = fmaf(cv.z, o1[4*d4+2], acc1);                                   \
      acc0 = fmaf(cv.w, o0[4*d4+3], acc0);                                   \
      acc1 = fmaf(cv.w, o1[4*d4+3], acc1);                                   \
    }                                                                        \
    const bool valid = (c0 + lane) < C_;                                     \
    float sc0 = fmaf(-2.f, acc0, s2v);                                       \
    float sc1 = fmaf(-2.f, acc1, s2v);                                       \
    sc0 = valid ? sc0 : INFINITY;                                            \
    sc1 = valid ? sc1 : INFINITY;                                            \
    SELECT_INSERT(sc0, best0, bix0, c0);                                     \
    SELECT_INSERT(sc1, best1, bix1, c0);                                     \
  }

  for (int tt = 0; tt < NT; tt += 2) {   // NT = 782 (even)
    BODY(0);
    BODY(1);
  }
#undef BODY

  // epilogue: gather qvals (broadcast loads), mean, write
  const float* qa = qv + (size_t)a * C_;
  float s0 = 0.f, s1 = 0.f;
  #pragma unroll
  for (int j = 0; j < K_NN; ++j) { s0 += qa[bix0[j]]; s1 += qa[bix1[j]]; }
  if (lane == 0) {
    qec[b0 * A_ + a] = s0 / (float)K_NN;
    qec[b1 * A_ + a] = s1 / (float)K_NN;
  }
}

// ---------------- K3: MLP + combine + argmax ----------------
__global__ __launch_bounds__(256) void mlp_kernel(
    const float* __restrict__ obs, const float* __restrict__ qec,
    const float* __restrict__ W1, const float* __restrict__ b1,
    const float* __restrict__ W2, const float* __restrict__ b2,
    const float* __restrict__ W3, const float* __restrict__ b3,
    float* __restrict__ out)
{
  const int wave = threadIdx.x >> 6;
  const int lane = threadIdx.x & 63;
  const int b = blockIdx.x * 4 + wave;

  float x = obs[(size_t)b * 64 + lane];

  float acc = b1[lane];
  #pragma unroll 8
  for (int d = 0; d < 64; ++d)
    acc = fmaf(__shfl(x, d, 64), W1[d * 64 + lane], acc);
  float h1 = fmaxf(acc, 0.f);

  float acc2 = b2[lane];
  #pragma unroll 8
  for (int d = 0; d < 64; ++d)
    acc2 = fmaf(__shfl(h1, d, 64), W2[d * 64 + lane], acc2);
  float h2 = fmaxf(acc2, 0.f);

  float p0 = h2 * W3[lane * 4 + 0];
  float p1 = h2 * W3[lane * 4 + 1];
  float p2 = h2 * W3[lane * 4 + 2];
  float p3 = h2 * W3[lane * 4 + 3];
  #pragma unroll
  for (int off = 32; off > 0; off >>= 1) {
    p0 += __shfl_xor(p0, off, 64);
    p1 += __shfl_xor(p1, off, 64);
    p2 += __shfl_xor(p2, off, 64);
    p3 += __shfl_xor(p3, off, 64);
  }

  if (lane == 0) {
    float q0 = 0.5f * (qec[b * 4 + 0] + (p0 + b3[0]));
    float q1 = 0.5f * (qec[b * 4 + 1] + (p1 + b3[1]));
    float q2 = 0.5f * (qec[b * 4 + 2] + (p2 + b3[2]));
    float q3 = 0.5f * (qec[b * 4 + 3] + (p3 + b3[3]));
    int am = 0; float m = q0;
    if (q1 > m) { m = q1; am = 1; }
    if (q2 > m) { m = q2; am = 2; }
    if (q3 > m) { m = q3; am = 3; }
    out[b] = (float)am;
    float* qrow = out + B_ + (size_t)b * 4;
    qrow[0] = q0; qrow[1] = q1; qrow[2] = q2; qrow[3] = q3;
  }
}

extern "C" void kernel_launch(void* const* d_in, const int* in_sizes, int n_in,
                              void* d_out, int out_size, void* d_ws, size_t ws_size,
                              hipStream_t stream) {
  const float* obs = (const float*)d_in[0];
  const float* ts  = (const float*)d_in[1];
  const float* qv  = (const float*)d_in[2];
  const float* W1  = (const float*)d_in[3];
  const float* b1  = (const float*)d_in[4];
  const float* W2  = (const float*)d_in[5];
  const float* b2  = (const float*)d_in[6];
  const float* W3  = (const float*)d_in[7];
  const float* b3  = (const float*)d_in[8];
  float* out = (float*)d_out;

  float* s2g = (float*)d_ws;                  // A*C floats
  float* qec = s2g + (size_t)A_ * C_;         // B*A floats

  s2_kernel<<<dim3((A_ * C_ / 16 + 3) / 4), dim3(256), 0, stream>>>(ts, s2g);
  qec_kernel<<<dim3(256), dim3(512), 0, stream>>>(obs, ts, s2g, qv, qec);
  mlp_kernel<<<dim3(B_ / 4), dim3(256), 0, stream>>>(obs, qec, W1, b1, W2, b2, W3, b3, out);
}